// Round 1
// baseline (643.631 us; speedup 1.0000x reference)
//
#include <hip/hip_runtime.h>
#include <hip/hip_bf16.h>
#include <math.h>

// Problem constants (fixed by setup_inputs)
constexpr int B_ = 32;
constexpr int P_ = 24564;
constexpr int C_ = 81;
constexpr int K_ = 200;

constexpr int NCHUNK = 16;
constexpr int CP = 1536;            // rows (p) per chunk; 16*1536 = 24576 >= 24564
constexpr int CAP = 1536;           // per-task candidate list capacity
constexpr int NBIN = 128;           // histogram bins over scorebits[31:19]
constexpr unsigned BIN_BASE = 0x780u; // (bits>>19) for exponent region starting at 2^-7

// ---------------------------------------------------------------------------
// K1: per-(b,chunk) block builds per-class 128-bin histograms of score bit
// prefixes, coalesced float4 reads over the conf slab. Partials to global.
// ---------------------------------------------------------------------------
__global__ __launch_bounds__(256) void k_hist(const float* __restrict__ conf,
                                              unsigned* __restrict__ partial) {
    __shared__ unsigned hist[C_ * NBIN];   // 81*128*4 = 41472 B
    const int bid = blockIdx.x;
    const int b = bid / NCHUNK, ch = bid % NCHUNK;
    for (int i = threadIdx.x; i < C_ * NBIN; i += 256) hist[i] = 0;
    __syncthreads();

    const int p0 = ch * CP;
    const int rows = min(CP, P_ - p0);
    const float* slab = conf + ((size_t)b * P_ + (size_t)p0) * C_;
    const int n4 = rows * C_ / 4;   // rows*81 is divisible by 4 for rows%4==0
    for (int g = threadIdx.x; g < n4; g += 256) {
        float4 v = ((const float4*)slab)[g];
        int e = g * 4;
        int c = e % C_;
        float s[4] = {v.x, v.y, v.z, v.w};
#pragma unroll
        for (int j = 0; j < 4; ++j) {
            int cj = c + j; if (cj >= C_) cj -= C_;
            float sv = s[j];
            if (sv > 0.01f) {
                unsigned ub = __float_as_uint(sv);
                int bin = (int)(ub >> 19) - (int)BIN_BASE;
                bin = max(0, min(NBIN - 1, bin));
                atomicAdd(&hist[cj * NBIN + bin], 1u);
            }
        }
    }
    __syncthreads();
    unsigned* dst = partial + (size_t)bid * (C_ * NBIN);
    for (int i = threadIdx.x; i < C_ * NBIN; i += 256) dst[i] = hist[i];
}

// ---------------------------------------------------------------------------
// K1.5: per task reduce partials, suffix-scan, pick threshold bin prefix.
// thr16[task] compared against (scorebits >> 19).
// ---------------------------------------------------------------------------
__global__ __launch_bounds__(128) void k_thresh(const unsigned* __restrict__ partial,
                                                unsigned* __restrict__ thr16) {
    __shared__ unsigned sf[NBIN];
    __shared__ int cb;
    const int task = blockIdx.x;
    const int b = task / C_, c = task % C_;
    const int tid = threadIdx.x;

    unsigned acc = 0;
    for (int ch = 0; ch < NCHUNK; ++ch)
        acc += partial[((size_t)(b * NCHUNK + ch) * C_ + c) * NBIN + tid];
    sf[tid] = acc;
    if (tid == 0) cb = 0;
    __syncthreads();
    // suffix sum: sf[t] = count of elements with bin >= t
    for (int off = 1; off < NBIN; off <<= 1) {
        unsigned v = (tid + off < NBIN) ? sf[tid + off] : 0u;
        __syncthreads();
        sf[tid] += v;
        __syncthreads();
    }
    // largest t with sf[t] >= K_ (rank-200 bin). If total < 200 -> 0 (take all).
    if (sf[tid] >= (unsigned)K_ && (tid == NBIN - 1 || sf[tid + 1] < (unsigned)K_)) cb = tid;
    __syncthreads();
    if (tid == 0) thr16[task] = (c == 0) ? 0xFFFFFFFFu : (BIN_BASE + (unsigned)cb);
}

// ---------------------------------------------------------------------------
// K2: second coalesced pass; append qualifying (scorebits, ~p) keys to
// per-task candidate lists. Append order nondeterministic; SET deterministic.
// ---------------------------------------------------------------------------
__global__ __launch_bounds__(256) void k_filter(const float* __restrict__ conf,
                                                const unsigned* __restrict__ thr16,
                                                unsigned long long* __restrict__ cand,
                                                unsigned* __restrict__ cnt) {
    __shared__ unsigned thr[C_];
    const int bid = blockIdx.x;
    const int b = bid / NCHUNK, ch = bid % NCHUNK;
    for (int i = threadIdx.x; i < C_; i += 256) thr[i] = thr16[b * C_ + i];
    __syncthreads();

    const int p0 = ch * CP;
    const int rows = min(CP, P_ - p0);
    const float* slab = conf + ((size_t)b * P_ + (size_t)p0) * C_;
    const int n4 = rows * C_ / 4;
    for (int g = threadIdx.x; g < n4; g += 256) {
        float4 v = ((const float4*)slab)[g];
        int e = g * 4;
        int c = e % C_;
        int pl = e / C_;
        float s[4] = {v.x, v.y, v.z, v.w};
#pragma unroll
        for (int j = 0; j < 4; ++j) {
            int cj = c + j, pj = pl;
            if (cj >= C_) { cj -= C_; pj += 1; }
            float sv = s[j];
            if (sv > 0.01f) {
                unsigned ub = __float_as_uint(sv);
                if ((ub >> 19) >= thr[cj]) {
                    int task = b * C_ + cj;
                    unsigned pos = atomicAdd(&cnt[task], 1u);
                    if (pos < (unsigned)CAP) {
                        unsigned pglob = (unsigned)(p0 + pj);
                        cand[(size_t)task * CAP + pos] =
                            ((unsigned long long)ub << 32) | (unsigned)(~pglob);
                    }
                }
            }
        }
    }
}

// ---------------------------------------------------------------------------
// K3: per-task exact top-200 (radix-select + bitonic sort), decode boxes,
// IoU bitmasks via ballot, serial suppression scan, compacted write.
// ---------------------------------------------------------------------------
__global__ __launch_bounds__(256) void k_nms(const unsigned long long* __restrict__ cand,
                                             const unsigned* __restrict__ cnt,
                                             const float* __restrict__ loc,
                                             const float* __restrict__ prior,
                                             float* __restrict__ out) {
#pragma clang fp contract(off)
    __shared__ unsigned long long buf[CAP];
    __shared__ unsigned long long top[256];
    __shared__ float sc[K_], bx1[K_], by1[K_], bx2[K_], by2[K_], bar[K_];
    __shared__ unsigned long long masks[K_][4];
    __shared__ unsigned rs_hist[256];
    __shared__ unsigned rs_sf[256];
    __shared__ unsigned long long sh_prefix;
    __shared__ unsigned sh_rank, sh_cnt2;
    __shared__ unsigned long long keepw[4];
    __shared__ unsigned kpre[4];
    __shared__ unsigned char vflag[K_];

    const int bid = blockIdx.x;
    const int b = bid / (C_ - 1), cc = bid % (C_ - 1);
    const int c = cc + 1;
    const int task = b * C_ + c;
    const int tid = threadIdx.x;

    const int n = (int)min(cnt[task], (unsigned)CAP);

    for (int i = tid; i < CAP; i += 256)
        buf[i] = (i < n) ? cand[(size_t)task * CAP + i] : 0ull;
    __syncthreads();

    const int nsel = min(n, K_);
    unsigned long long t200 = 1ull;   // n <= K_: take everything (keys are nonzero)

    if (n > K_) {
        if (tid == 0) { sh_prefix = 0ull; sh_rank = (unsigned)K_; }
        __syncthreads();
        for (int d = 7; d >= 0; --d) {
            rs_hist[tid] = 0;
            __syncthreads();
            const unsigned long long pref = sh_prefix;
            const unsigned rank = sh_rank;
            for (int i = tid; i < n; i += 256) {
                unsigned long long key = buf[i];
                bool match = (d == 7) || (((key ^ pref) >> ((d + 1) * 8)) == 0ull);
                if (match) atomicAdd(&rs_hist[(unsigned)((key >> (d * 8)) & 255ull)], 1u);
            }
            __syncthreads();
            unsigned h = rs_hist[tid];
            rs_sf[tid] = h;
            __syncthreads();
            for (int off = 1; off < 256; off <<= 1) {
                unsigned v = (tid + off < 256) ? rs_sf[tid + off] : 0u;
                __syncthreads();
                rs_sf[tid] += v;
                __syncthreads();
            }
            if (rs_sf[tid] >= rank && (tid == 255 || rs_sf[tid + 1] < rank)) {
                sh_prefix = pref | ((unsigned long long)tid << (d * 8));
                sh_rank = rank - ((tid == 255) ? 0u : rs_sf[tid + 1]);
            }
            __syncthreads();
        }
        t200 = sh_prefix;   // exact 200th-largest key (keys unique)
    }

    // compact candidates >= t200 into top[] (exactly nsel of them), pad zeros
    top[tid] = 0ull;
    if (tid == 0) sh_cnt2 = 0;
    __syncthreads();
    for (int i = tid; i < n; i += 256) {
        unsigned long long key = buf[i];
        if (key >= t200 && key != 0ull) {
            unsigned pos = atomicAdd(&sh_cnt2, 1u);
            if (pos < 256u) top[pos] = key;
        }
    }
    __syncthreads();

    // bitonic sort ascending over 256 keys
    for (int k = 2; k <= 256; k <<= 1) {
        for (int j = k >> 1; j > 0; j >>= 1) {
            int i = tid, partner = i ^ j;
            if (partner > i) {
                bool up = ((i & k) == 0);
                unsigned long long a = top[i], bb = top[partner];
                if ((a > bb) == up) { top[i] = bb; top[partner] = a; }
            }
            __syncthreads();
        }
    }

    // decode rank-r candidates (descending = top[255 - r])
    if (tid < K_) {
        const int r = tid;
        bool v = (r < nsel);
        float score = 0.f, x1 = 0.f, y1 = 0.f, x2 = 0.f, y2 = 0.f, ar = 0.f;
        if (v) {
            unsigned long long key = top[255 - r];
            unsigned ub = (unsigned)(key >> 32);
            unsigned p = ~((unsigned)key);
            score = __uint_as_float(ub);
            v = ((ub & 0x7F800000u) != 0x7F800000u);   // isfinite
            const float4 l4 = ((const float4*)loc)[(size_t)b * P_ + p];
            const float4 p4 = ((const float4*)prior)[p];
            // replicate reference decode op-for-op (no FMA contraction)
            float cx = p4.x + (l4.x * 0.1f) * p4.z;
            float cy = p4.y + (l4.y * 0.1f) * p4.w;
            float w  = p4.z * expf(l4.z * 0.2f);
            float h  = p4.w * expf(l4.w * 0.2f);
            x1 = cx - w * 0.5f;
            y1 = cy - h * 0.5f;
            x2 = x1 + w;
            y2 = y1 + h;
            ar = (x2 - x1) * (y2 - y1);
        }
        sc[r] = score; bx1[r] = x1; by1[r] = y1; bx2[r] = x2; by2[r] = y2; bar[r] = ar;
        vflag[r] = v ? (unsigned char)1 : (unsigned char)0;
    }
    __syncthreads();

    // IoU suppression bitmasks: wave handles (row i, 64-bit word w)
    const int nv = nsel;
    const int wid = tid >> 6, lane = tid & 63;
    for (int u = wid; u < nv * 4; u += 4) {
        int i = u >> 2, w = u & 3;
        int j = w * 64 + lane;
        bool pred = false;
        if (j < nv && j > i) {
            float xx1 = fmaxf(bx1[i], bx1[j]);
            float yy1 = fmaxf(by1[i], by1[j]);
            float xx2 = fminf(bx2[i], bx2[j]);
            float yy2 = fminf(by2[i], by2[j]);
            float iw = fmaxf(xx2 - xx1, 0.0f);
            float ih = fmaxf(yy2 - yy1, 0.0f);
            float inter = iw * ih;
            float uni = (bar[i] + bar[j]) - inter;
            pred = (uni > 0.0f) && (inter / uni > 0.45f);
        }
        unsigned long long m = __ballot(pred);
        if (lane == 0) masks[i][w] = m;
    }
    __syncthreads();

    // serial greedy suppression (bit ops only)
    if (tid == 0) {
        unsigned long long s0 = 0, s1 = 0, s2 = 0, s3 = 0;
        unsigned long long k0 = 0, k1 = 0, k2 = 0, k3 = 0;
        for (int i = 0; i < nv; ++i) {
            int w = i >> 6, bit = i & 63;
            unsigned long long sw = (w == 0) ? s0 : (w == 1) ? s1 : (w == 2) ? s2 : s3;
            if (vflag[i] && !((sw >> bit) & 1ull)) {
                if (w == 0) k0 |= 1ull << bit;
                else if (w == 1) k1 |= 1ull << bit;
                else if (w == 2) k2 |= 1ull << bit;
                else k3 |= 1ull << bit;
                s0 |= masks[i][0]; s1 |= masks[i][1]; s2 |= masks[i][2]; s3 |= masks[i][3];
            }
        }
        keepw[0] = k0; keepw[1] = k1; keepw[2] = k2; keepw[3] = k3;
        kpre[0] = 0;
        kpre[1] = (unsigned)__popcll(k0);
        kpre[2] = kpre[1] + (unsigned)__popcll(k1);
        kpre[3] = kpre[2] + (unsigned)__popcll(k2);
    }
    __syncthreads();

    if (tid < nv) {
        int w = tid >> 6, bit = tid & 63;
        if ((keepw[w] >> bit) & 1ull) {
            unsigned slot = kpre[w] + (unsigned)__popcll(keepw[w] & ((1ull << bit) - 1ull));
            float* o = out + ((size_t)task * K_ + slot) * 5;
            o[0] = sc[tid]; o[1] = bx1[tid]; o[2] = by1[tid]; o[3] = bx2[tid]; o[4] = by2[tid];
        }
    }
}

// ---------------------------------------------------------------------------
extern "C" void kernel_launch(void* const* d_in, const int* in_sizes, int n_in,
                              void* d_out, int out_size, void* d_ws, size_t ws_size,
                              hipStream_t stream) {
    const float* loc   = (const float*)d_in[0];
    const float* conf  = (const float*)d_in[1];
    const float* prior = (const float*)d_in[2];
    float* out = (float*)d_out;

    // ws layout: region A (aliased: K1 partial hists, then K2/K3 cand lists),
    // then cnt, then thr16. Lifetimes are disjoint (stream-ordered).
    char* ws = (char*)d_ws;
    const size_t candBytes = (size_t)B_ * C_ * CAP * sizeof(unsigned long long); // 31,850,496
    // partial hists need 32*16*81*128*4 = 21,233,664 <= candBytes
    unsigned long long* cand = (unsigned long long*)ws;
    unsigned* partial        = (unsigned*)ws;
    unsigned* cnt            = (unsigned*)(ws + candBytes);
    unsigned* thr16          = (unsigned*)(ws + candBytes + (size_t)B_ * C_ * sizeof(unsigned));

    hipMemsetAsync(d_out, 0, (size_t)out_size * sizeof(float), stream);
    hipMemsetAsync(cnt, 0, (size_t)B_ * C_ * sizeof(unsigned), stream);

    k_hist  <<<B_ * NCHUNK, 256, 0, stream>>>(conf, partial);
    k_thresh<<<B_ * C_,     128, 0, stream>>>(partial, thr16);
    k_filter<<<B_ * NCHUNK, 256, 0, stream>>>(conf, thr16, cand, cnt);
    k_nms   <<<B_ * (C_-1), 256, 0, stream>>>(cand, cnt, loc, prior, out);
}

// Round 2
// 389.291 us; speedup vs baseline: 1.6533x; 1.6533x over previous
//
#include <hip/hip_runtime.h>
#include <hip/hip_bf16.h>
#include <math.h>

// Problem constants (fixed by setup_inputs)
constexpr int B_ = 32;
constexpr int P_ = 24564;
constexpr int C_ = 81;
constexpr int K_ = 200;

constexpr int NCH = 64;          // chunks per image
constexpr int CPR = 384;         // rows per chunk; 64*384 = 24576 >= 24564
constexpr int SCAP = 2048;       // per-block LDS staging capacity (expect ~972)
constexpr int CAP  = 1024;       // per-task candidate capacity (expect ~768)
constexpr float T_SEL = 0.96875f; // static prune threshold; soundness checked at runtime

// ---------------------------------------------------------------------------
// K1 (only conf pass): stream slab coalesced, stage score>T candidates in LDS,
// reserve per-class ranges with ONE global atomic per (block,class), scatter.
// ---------------------------------------------------------------------------
__global__ __launch_bounds__(256) void k_filter(const float* __restrict__ conf,
                                                unsigned long long* __restrict__ cand,
                                                unsigned* __restrict__ cnt,
                                                unsigned* __restrict__ bflag) {
    __shared__ unsigned long long skey[SCAP];   // 16 KB
    __shared__ unsigned short scls[SCAP];       // 4 KB
    __shared__ unsigned scnt[C_], sbase[C_], scnt2[C_];
    __shared__ unsigned sn;
    const int bid = blockIdx.x;
    const int b = bid / NCH, ch = bid % NCH;
    const int tid = threadIdx.x;

    for (int i = tid; i < C_; i += 256) { scnt[i] = 0; scnt2[i] = 0; }
    if (tid == 0) sn = 0;
    __syncthreads();

    const int p0 = ch * CPR;
    const int rows = min(CPR, P_ - p0);
    const float* slab = conf + ((size_t)b * P_ + (size_t)p0) * C_;
    const int n4 = rows * C_ / 4;              // rows%4==0 -> exact
    for (int g = tid; g < n4; g += 256) {
        float4 v = ((const float4*)slab)[g];
        int e = g * 4;
        int c = e % C_;
        int pl = e / C_;
        float s[4] = {v.x, v.y, v.z, v.w};
#pragma unroll
        for (int j = 0; j < 4; ++j) {
            int cj = c + j, pj = pl;
            if (cj >= C_) { cj -= C_; pj += 1; }
            float sv = s[j];
            if (sv > T_SEL && cj != 0) {       // class 0 (background) never output
                unsigned pos = atomicAdd(&sn, 1u);
                if (pos < (unsigned)SCAP) {
                    unsigned pg = (unsigned)(p0 + pj);
                    skey[pos] = ((unsigned long long)__float_as_uint(sv) << 32) | (~pg);
                    scls[pos] = (unsigned short)cj;
                    atomicAdd(&scnt[cj], 1u);
                } else {
                    bflag[b] = 1u;             // staging overflow -> image fallback
                }
            }
        }
    }
    __syncthreads();
    if (tid < C_) sbase[tid] = scnt[tid] ? atomicAdd(&cnt[b * C_ + tid], scnt[tid]) : 0u;
    __syncthreads();
    const int m = (int)min(sn, (unsigned)SCAP);
    for (int i = tid; i < m; i += 256) {
        int c = scls[i];
        unsigned pos = sbase[c] + atomicAdd(&scnt2[c], 1u);
        if (pos < (unsigned)CAP)
            cand[((size_t)(b * C_ + c)) * CAP + pos] = skey[i];
        // pos >= CAP  =>  cnt[task] > CAP  => task falls back (detected in k_nms)
    }
}

// ---------------------------------------------------------------------------
// K2: per-task exact top-200 (radix-select + bitonic sort), decode, IoU masks,
// serial suppression, compacted rows assembled in LDS, coalesced write.
// Block-uniform fallback path does exact selection from the global column.
// ---------------------------------------------------------------------------
__global__ __launch_bounds__(256) void k_nms(const unsigned long long* __restrict__ cand,
                                             const unsigned* __restrict__ cnt,
                                             const unsigned* __restrict__ bflag,
                                             const float* __restrict__ conf,
                                             const float* __restrict__ loc,
                                             const float* __restrict__ prior,
                                             float* __restrict__ out) {
#pragma clang fp contract(off)
    __shared__ unsigned long long buf[CAP];
    __shared__ unsigned long long top[256];
    __shared__ float sc[K_], bx1[K_], by1[K_], bx2[K_], by2[K_], bar[K_];
    __shared__ unsigned long long masks[K_][4];
    __shared__ unsigned rs_hist[256], rs_sf[256];
    __shared__ unsigned long long sh_prefix;
    __shared__ unsigned sh_rank, sh_cnt2;
    __shared__ unsigned long long keepw[4];
    __shared__ unsigned kpre[4];
    __shared__ unsigned char vflag[K_];
    __shared__ __align__(16) float outrow[K_ * 5];

    const int bid = blockIdx.x;
    const int b = bid / C_, c = bid % C_;
    const int tid = threadIdx.x;
    float* obase = out + ((size_t)(b * C_ + c)) * (K_ * 5);

    if (c == 0) {                              // background rows: all zeros
        float4 z = make_float4(0.f, 0.f, 0.f, 0.f);
        for (int i = tid; i < K_ * 5 / 4; i += 256) ((float4*)obase)[i] = z;
        return;
    }
    for (int i = tid; i < K_ * 5; i += 256) outrow[i] = 0.0f;

    const int task = b * C_ + c;
    const unsigned cn = cnt[task];
    const bool fb = (bflag[b] != 0u) || (cn < (unsigned)K_) || (cn > (unsigned)CAP);

    int n;
    if (!fb) {
        n = (int)cn;                           // 200 <= n <= CAP
        for (int i = tid; i < n; i += 256) buf[i] = cand[(size_t)task * CAP + i];
        __syncthreads();
    } else {
        // ---- exact fallback from the strided global column (rare/never) ----
        const float* col = conf + (size_t)b * P_ * C_ + c;
        unsigned lc = 0;
        for (int p = tid; p < P_; p += 256)
            if (col[(size_t)p * C_] > 0.01f) lc++;
        rs_sf[tid] = lc;
        __syncthreads();
        for (int off = 128; off > 0; off >>= 1) {
            if (tid < off) rs_sf[tid] += rs_sf[tid + off];
            __syncthreads();
        }
        const unsigned total = rs_sf[0];
        unsigned long long t200v = 1ull;
        if (total > (unsigned)K_) {
            if (tid == 0) { sh_prefix = 0ull; sh_rank = (unsigned)K_; }
            __syncthreads();
            for (int d = 7; d >= 0; --d) {
                rs_hist[tid] = 0;
                __syncthreads();
                const unsigned long long pref = sh_prefix;
                const unsigned rank = sh_rank;
                for (int p = tid; p < P_; p += 256) {
                    float sv = col[(size_t)p * C_];
                    if (sv > 0.01f) {
                        unsigned long long key =
                            ((unsigned long long)__float_as_uint(sv) << 32) | (~(unsigned)p);
                        bool match = (d == 7) || (((key ^ pref) >> ((d + 1) * 8)) == 0ull);
                        if (match) atomicAdd(&rs_hist[(unsigned)((key >> (d * 8)) & 255ull)], 1u);
                    }
                }
                __syncthreads();
                rs_sf[tid] = rs_hist[tid];
                __syncthreads();
                for (int off = 1; off < 256; off <<= 1) {
                    unsigned v2 = (tid + off < 256) ? rs_sf[tid + off] : 0u;
                    __syncthreads();
                    rs_sf[tid] += v2;
                    __syncthreads();
                }
                if (rs_sf[tid] >= rank && (tid == 255 || rs_sf[tid + 1] < rank)) {
                    sh_prefix = pref | ((unsigned long long)tid << (d * 8));
                    sh_rank = rank - ((tid == 255) ? 0u : rs_sf[tid + 1]);
                }
                __syncthreads();
            }
            t200v = sh_prefix;
        }
        if (tid == 0) sh_cnt2 = 0;
        __syncthreads();
        for (int p = tid; p < P_; p += 256) {
            float sv = col[(size_t)p * C_];
            if (sv > 0.01f) {
                unsigned long long key =
                    ((unsigned long long)__float_as_uint(sv) << 32) | (~(unsigned)p);
                if (key >= t200v) {
                    unsigned pos = atomicAdd(&sh_cnt2, 1u);
                    if (pos < (unsigned)CAP) buf[pos] = key;
                }
            }
        }
        __syncthreads();
        n = (int)min(sh_cnt2, (unsigned)CAP);  // <= K_ by exactness
    }

    const int nsel = min(n, K_);
    unsigned long long t200 = 1ull;

    if (n > K_) {                              // exact 200th key via radix select on buf
        if (tid == 0) { sh_prefix = 0ull; sh_rank = (unsigned)K_; }
        __syncthreads();
        for (int d = 7; d >= 0; --d) {
            rs_hist[tid] = 0;
            __syncthreads();
            const unsigned long long pref = sh_prefix;
            const unsigned rank = sh_rank;
            for (int i = tid; i < n; i += 256) {
                unsigned long long key = buf[i];
                bool match = (d == 7) || (((key ^ pref) >> ((d + 1) * 8)) == 0ull);
                if (match) atomicAdd(&rs_hist[(unsigned)((key >> (d * 8)) & 255ull)], 1u);
            }
            __syncthreads();
            rs_sf[tid] = rs_hist[tid];
            __syncthreads();
            for (int off = 1; off < 256; off <<= 1) {
                unsigned v2 = (tid + off < 256) ? rs_sf[tid + off] : 0u;
                __syncthreads();
                rs_sf[tid] += v2;
                __syncthreads();
            }
            if (rs_sf[tid] >= rank && (tid == 255 || rs_sf[tid + 1] < rank)) {
                sh_prefix = pref | ((unsigned long long)tid << (d * 8));
                sh_rank = rank - ((tid == 255) ? 0u : rs_sf[tid + 1]);
            }
            __syncthreads();
        }
        t200 = sh_prefix;
    }

    // compact candidates >= t200 into top[] (exactly nsel), pad zeros
    top[tid] = 0ull;
    if (tid == 0) sh_cnt2 = 0;
    __syncthreads();
    for (int i = tid; i < n; i += 256) {
        unsigned long long key = buf[i];
        if (key >= t200 && key != 0ull) {
            unsigned pos = atomicAdd(&sh_cnt2, 1u);
            if (pos < 256u) top[pos] = key;
        }
    }
    __syncthreads();

    // bitonic sort ascending over 256 keys
    for (int k = 2; k <= 256; k <<= 1) {
        for (int j = k >> 1; j > 0; j >>= 1) {
            int i = tid, partner = i ^ j;
            if (partner > i) {
                bool up = ((i & k) == 0);
                unsigned long long a = top[i], bb = top[partner];
                if ((a > bb) == up) { top[i] = bb; top[partner] = a; }
            }
            __syncthreads();
        }
    }

    // decode rank-r candidates (descending = top[255 - r])
    if (tid < K_) {
        const int r = tid;
        bool v = (r < nsel);
        float score = 0.f, x1 = 0.f, y1 = 0.f, x2 = 0.f, y2 = 0.f, ar = 0.f;
        if (v) {
            unsigned long long key = top[255 - r];
            unsigned ub = (unsigned)(key >> 32);
            unsigned p = ~((unsigned)key);
            score = __uint_as_float(ub);
            v = ((ub & 0x7F800000u) != 0x7F800000u);   // isfinite
            const float4 l4 = ((const float4*)loc)[(size_t)b * P_ + p];
            const float4 p4 = ((const float4*)prior)[p];
            float cx = p4.x + (l4.x * 0.1f) * p4.z;
            float cy = p4.y + (l4.y * 0.1f) * p4.w;
            float w  = p4.z * expf(l4.z * 0.2f);
            float h  = p4.w * expf(l4.w * 0.2f);
            x1 = cx - w * 0.5f;
            y1 = cy - h * 0.5f;
            x2 = x1 + w;
            y2 = y1 + h;
            ar = (x2 - x1) * (y2 - y1);
        }
        sc[r] = score; bx1[r] = x1; by1[r] = y1; bx2[r] = x2; by2[r] = y2; bar[r] = ar;
        vflag[r] = v ? (unsigned char)1 : (unsigned char)0;
    }
    __syncthreads();

    // IoU suppression bitmasks: wave handles (row i, 64-bit word w)
    const int nv = nsel;
    const int wid = tid >> 6, lane = tid & 63;
    for (int u = wid; u < nv * 4; u += 4) {
        int i = u >> 2, w = u & 3;
        int j = w * 64 + lane;
        bool pred = false;
        if (j < nv && j > i) {
            float xx1 = fmaxf(bx1[i], bx1[j]);
            float yy1 = fmaxf(by1[i], by1[j]);
            float xx2 = fminf(bx2[i], bx2[j]);
            float yy2 = fminf(by2[i], by2[j]);
            float iw = fmaxf(xx2 - xx1, 0.0f);
            float ih = fmaxf(yy2 - yy1, 0.0f);
            float inter = iw * ih;
            float uni = (bar[i] + bar[j]) - inter;
            pred = (uni > 0.0f) && (inter / uni > 0.45f);
        }
        unsigned long long m = __ballot(pred);
        if (lane == 0) masks[i][w] = m;
    }
    __syncthreads();

    // serial greedy suppression (bit ops only)
    if (tid == 0) {
        unsigned long long s0 = 0, s1 = 0, s2 = 0, s3 = 0;
        unsigned long long k0 = 0, k1 = 0, k2 = 0, k3 = 0;
        for (int i = 0; i < nv; ++i) {
            int w = i >> 6, bit = i & 63;
            unsigned long long sw = (w == 0) ? s0 : (w == 1) ? s1 : (w == 2) ? s2 : s3;
            if (vflag[i] && !((sw >> bit) & 1ull)) {
                if (w == 0) k0 |= 1ull << bit;
                else if (w == 1) k1 |= 1ull << bit;
                else if (w == 2) k2 |= 1ull << bit;
                else k3 |= 1ull << bit;
                s0 |= masks[i][0]; s1 |= masks[i][1]; s2 |= masks[i][2]; s3 |= masks[i][3];
            }
        }
        keepw[0] = k0; keepw[1] = k1; keepw[2] = k2; keepw[3] = k3;
        kpre[0] = 0;
        kpre[1] = (unsigned)__popcll(k0);
        kpre[2] = kpre[1] + (unsigned)__popcll(k1);
        kpre[3] = kpre[2] + (unsigned)__popcll(k2);
    }
    __syncthreads();

    if (tid < nv) {
        int w = tid >> 6, bit = tid & 63;
        if ((keepw[w] >> bit) & 1ull) {
            unsigned slot = kpre[w] + (unsigned)__popcll(keepw[w] & ((1ull << bit) - 1ull));
            outrow[slot * 5 + 0] = sc[tid];
            outrow[slot * 5 + 1] = bx1[tid];
            outrow[slot * 5 + 2] = by1[tid];
            outrow[slot * 5 + 3] = bx2[tid];
            outrow[slot * 5 + 4] = by2[tid];
        }
    }
    __syncthreads();

    for (int i = tid; i < K_ * 5 / 4; i += 256)
        ((float4*)obase)[i] = ((const float4*)outrow)[i];
}

// ---------------------------------------------------------------------------
extern "C" void kernel_launch(void* const* d_in, const int* in_sizes, int n_in,
                              void* d_out, int out_size, void* d_ws, size_t ws_size,
                              hipStream_t stream) {
    const float* loc   = (const float*)d_in[0];
    const float* conf  = (const float*)d_in[1];
    const float* prior = (const float*)d_in[2];
    float* out = (float*)d_out;

    char* ws = (char*)d_ws;
    const size_t candBytes = (size_t)B_ * C_ * CAP * sizeof(unsigned long long); // 21.2 MB
    unsigned long long* cand = (unsigned long long*)ws;
    unsigned* cnt   = (unsigned*)(ws + candBytes);            // B_*C_ counters
    unsigned* bflag = cnt + (size_t)B_ * C_;                  // B_ flags (contiguous)

    hipMemsetAsync(cnt, 0, (size_t)(B_ * C_ + B_) * sizeof(unsigned), stream);

    k_filter<<<B_ * NCH, 256, 0, stream>>>(conf, cand, cnt, bflag);
    k_nms   <<<B_ * C_,  256, 0, stream>>>(cand, cnt, bflag, conf, loc, prior, out);
}

// Round 3
// 229.026 us; speedup vs baseline: 2.8103x; 1.6998x over previous
//
#include <hip/hip_runtime.h>
#include <hip/hip_bf16.h>
#include <math.h>

// Problem constants (fixed by setup_inputs)
constexpr int B_ = 32;
constexpr int P_ = 24564;
constexpr int C_ = 81;
constexpr int K_ = 200;

constexpr int NCH = 64;           // chunks per image
constexpr int CPR = 384;          // rows per chunk; 64*384 = 24576 >= 24564
constexpr int SCAP = 1024;        // per-block LDS staging capacity (expect ~404)
constexpr int CAP  = 512;         // per-task candidate capacity (expect ~322)
constexpr int NSORT = 512;        // bitonic sort width (CAP)
constexpr float T_SEL = 0.9869f;  // static prune threshold; mean count ~322 > 200 (6.8 sigma)
                                  // soundness: count>=200 above T => true top-200 all > T;
                                  // violations detected at runtime -> exact fallback.

// ---------------------------------------------------------------------------
// K1 (only conf pass): stream slab coalesced, stage score>T candidates in LDS,
// reserve per-class ranges with ONE global atomic per (block,class), scatter.
// ---------------------------------------------------------------------------
__global__ __launch_bounds__(256) void k_filter(const float* __restrict__ conf,
                                                unsigned long long* __restrict__ cand,
                                                unsigned* __restrict__ cnt,
                                                unsigned* __restrict__ bflag) {
    __shared__ unsigned long long skey[SCAP];   // 8 KB
    __shared__ unsigned short scls[SCAP];       // 2 KB
    __shared__ unsigned scnt[C_], sbase[C_], scnt2[C_];
    __shared__ unsigned sn;
    const int bid = blockIdx.x;
    const int b = bid / NCH, ch = bid % NCH;
    const int tid = threadIdx.x;

    for (int i = tid; i < C_; i += 256) { scnt[i] = 0; scnt2[i] = 0; }
    if (tid == 0) sn = 0;
    __syncthreads();

    const int p0 = ch * CPR;
    const int rows = min(CPR, P_ - p0);
    const float* slab = conf + ((size_t)b * P_ + (size_t)p0) * C_;
    const int n4 = rows * C_ / 4;               // rows%4==0 -> exact
    for (int g = tid; g < n4; g += 256) {
        float4 v = ((const float4*)slab)[g];
        int e = g * 4;
        int c = e % C_;
        int pl = e / C_;
        float s[4] = {v.x, v.y, v.z, v.w};
#pragma unroll
        for (int j = 0; j < 4; ++j) {
            int cj = c + j, pj = pl;
            if (cj >= C_) { cj -= C_; pj += 1; }
            float sv = s[j];
            if (sv > T_SEL && cj != 0) {        // class 0 (background) never output
                unsigned pos = atomicAdd(&sn, 1u);
                if (pos < (unsigned)SCAP) {
                    unsigned pg = (unsigned)(p0 + pj);
                    skey[pos] = ((unsigned long long)__float_as_uint(sv) << 32) | (~pg);
                    scls[pos] = (unsigned short)cj;
                    atomicAdd(&scnt[cj], 1u);
                } else {
                    bflag[b] = 1u;              // staging overflow -> image fallback
                }
            }
        }
    }
    __syncthreads();
    if (tid < C_) sbase[tid] = scnt[tid] ? atomicAdd(&cnt[b * C_ + tid], scnt[tid]) : 0u;
    __syncthreads();
    const int m = (int)min(sn, (unsigned)SCAP);
    for (int i = tid; i < m; i += 256) {
        int c = scls[i];
        unsigned pos = sbase[c] + atomicAdd(&scnt2[c], 1u);
        if (pos < (unsigned)CAP)
            cand[((size_t)(b * C_ + c)) * CAP + pos] = skey[i];
        // pos >= CAP  =>  cnt[task] > CAP  => task falls back (detected in k_nms)
    }
}

// ---------------------------------------------------------------------------
// K2: per-task bitonic sort of <=512 keys (exact top-200 incl. tie-break),
// decode, IoU masks, serial suppression, compacted coalesced write.
// Block-uniform fallback path does exact selection from the global column.
// ---------------------------------------------------------------------------
__global__ __launch_bounds__(256) void k_nms(const unsigned long long* __restrict__ cand,
                                             const unsigned* __restrict__ cnt,
                                             const unsigned* __restrict__ bflag,
                                             const float* __restrict__ conf,
                                             const float* __restrict__ loc,
                                             const float* __restrict__ prior,
                                             float* __restrict__ out) {
#pragma clang fp contract(off)
    __shared__ unsigned long long buf[NSORT];           // 4 KB (sorted in place)
    __shared__ float sc[K_], bx1[K_], by1[K_], bx2[K_], by2[K_], bar[K_];
    __shared__ unsigned long long masks[K_][4];         // 6.4 KB
    __shared__ unsigned long long sh_prefix;
    __shared__ unsigned sh_rank, sh_cnt2;
    __shared__ unsigned long long keepw[4];
    __shared__ unsigned kpre[4];
    __shared__ unsigned char vflag[K_];
    __shared__ __align__(16) float outrow[K_ * 5];      // 4 KB

    // fallback-only radix scratch aliased onto masks (masks unused until IoU)
    unsigned* rs_hist = (unsigned*)&masks[0][0];
    unsigned* rs_sf   = rs_hist + 256;

    const int bid = blockIdx.x;
    const int b = bid / C_, c = bid % C_;
    const int tid = threadIdx.x;
    float* obase = out + ((size_t)(b * C_ + c)) * (K_ * 5);

    if (c == 0) {                               // background rows: all zeros
        float4 z = make_float4(0.f, 0.f, 0.f, 0.f);
        for (int i = tid; i < K_ * 5 / 4; i += 256) ((float4*)obase)[i] = z;
        return;
    }
    for (int i = tid; i < K_ * 5; i += 256) outrow[i] = 0.0f;

    const int task = b * C_ + c;
    const unsigned cn = cnt[task];
    const bool fb = (bflag[b] != 0u) || (cn < (unsigned)K_) || (cn > (unsigned)CAP);

    int n;
    if (!fb) {
        n = (int)cn;                            // 200 <= n <= CAP
        for (int i = tid; i < NSORT; i += 256)
            buf[i] = (i < n) ? cand[(size_t)task * CAP + i] : 0ull;
        __syncthreads();
    } else {
        // ---- exact fallback from the strided global column (rare/never) ----
        for (int i = tid; i < NSORT; i += 256) buf[i] = 0ull;
        const float* col = conf + (size_t)b * P_ * C_ + c;
        unsigned lc = 0;
        for (int p = tid; p < P_; p += 256)
            if (col[(size_t)p * C_] > 0.01f) lc++;
        rs_sf[tid] = lc;
        __syncthreads();
        for (int off = 128; off > 0; off >>= 1) {
            if (tid < off) rs_sf[tid] += rs_sf[tid + off];
            __syncthreads();
        }
        const unsigned total = rs_sf[0];
        unsigned long long t200v = 1ull;
        if (total > (unsigned)K_) {
            if (tid == 0) { sh_prefix = 0ull; sh_rank = (unsigned)K_; }
            __syncthreads();
            for (int d = 7; d >= 0; --d) {
                rs_hist[tid] = 0;
                __syncthreads();
                const unsigned long long pref = sh_prefix;
                const unsigned rank = sh_rank;
                for (int p = tid; p < P_; p += 256) {
                    float sv = col[(size_t)p * C_];
                    if (sv > 0.01f) {
                        unsigned long long key =
                            ((unsigned long long)__float_as_uint(sv) << 32) | (~(unsigned)p);
                        bool match = (d == 7) || (((key ^ pref) >> ((d + 1) * 8)) == 0ull);
                        if (match) atomicAdd(&rs_hist[(unsigned)((key >> (d * 8)) & 255ull)], 1u);
                    }
                }
                __syncthreads();
                rs_sf[tid] = rs_hist[tid];
                __syncthreads();
                for (int off = 1; off < 256; off <<= 1) {
                    unsigned v2 = (tid + off < 256) ? rs_sf[tid + off] : 0u;
                    __syncthreads();
                    rs_sf[tid] += v2;
                    __syncthreads();
                }
                if (rs_sf[tid] >= rank && (tid == 255 || rs_sf[tid + 1] < rank)) {
                    sh_prefix = pref | ((unsigned long long)tid << (d * 8));
                    sh_rank = rank - ((tid == 255) ? 0u : rs_sf[tid + 1]);
                }
                __syncthreads();
            }
            t200v = sh_prefix;
        }
        if (tid == 0) sh_cnt2 = 0;
        __syncthreads();
        for (int p = tid; p < P_; p += 256) {
            float sv = col[(size_t)p * C_];
            if (sv > 0.01f) {
                unsigned long long key =
                    ((unsigned long long)__float_as_uint(sv) << 32) | (~(unsigned)p);
                if (key >= t200v) {
                    unsigned pos = atomicAdd(&sh_cnt2, 1u);
                    if (pos < (unsigned)CAP) buf[pos] = key;   // exactly <=200 qualify
                }
            }
        }
        __syncthreads();
        n = (int)min(sh_cnt2, (unsigned)CAP);
    }

    // ---- bitonic sort ascending over NSORT=512 keys, 256 threads ----------
    for (int k = 2; k <= NSORT; k <<= 1) {
        for (int j = k >> 1; j > 0; j >>= 1) {
            int e = ((tid & ~(j - 1)) << 1) | (tid & (j - 1));
            int pp = e | j;
            bool up = ((e & k) == 0);
            unsigned long long a = buf[e], bb = buf[pp];
            unsigned long long lo = a < bb ? a : bb;
            unsigned long long hi = a < bb ? bb : a;
            buf[e]  = up ? lo : hi;
            buf[pp] = up ? hi : lo;
            __syncthreads();
        }
    }

    const int nsel = min(n, K_);

    // decode rank-r candidates (descending = buf[NSORT-1-r])
    if (tid < K_) {
        const int r = tid;
        bool v = (r < nsel);
        float score = 0.f, x1 = 0.f, y1 = 0.f, x2 = 0.f, y2 = 0.f, ar = 0.f;
        if (v) {
            unsigned long long key = buf[NSORT - 1 - r];
            unsigned ub = (unsigned)(key >> 32);
            unsigned p = ~((unsigned)key);
            score = __uint_as_float(ub);
            v = ((ub & 0x7F800000u) != 0x7F800000u);   // isfinite
            const float4 l4 = ((const float4*)loc)[(size_t)b * P_ + p];
            const float4 p4 = ((const float4*)prior)[p];
            float cx = p4.x + (l4.x * 0.1f) * p4.z;
            float cy = p4.y + (l4.y * 0.1f) * p4.w;
            float w  = p4.z * expf(l4.z * 0.2f);
            float h  = p4.w * expf(l4.w * 0.2f);
            x1 = cx - w * 0.5f;
            y1 = cy - h * 0.5f;
            x2 = x1 + w;
            y2 = y1 + h;
            ar = (x2 - x1) * (y2 - y1);
        }
        sc[r] = score; bx1[r] = x1; by1[r] = y1; bx2[r] = x2; by2[r] = y2; bar[r] = ar;
        vflag[r] = v ? (unsigned char)1 : (unsigned char)0;
    }
    __syncthreads();

    // IoU suppression bitmasks. Wave `wid` handles rows i == wid (mod 4),
    // words w in [i>>6, 4) (bits j<=i are always 0 -> skipped words zeroed here,
    // disjoint writes, no extra barrier needed).
    const int nv = nsel;
    const int wid = tid >> 6, lane = tid & 63;
    for (int idx = tid; idx < K_ * 4; idx += 256) {
        int i = idx >> 2, w = idx & 3;
        if (w < (i >> 6)) masks[i][w] = 0ull;
    }
    for (int i = wid; i < nv; i += 4) {
        float r_x1 = bx1[i], r_y1 = by1[i], r_x2 = bx2[i], r_y2 = by2[i], r_ar = bar[i];
        for (int w = (i >> 6); w < 4; ++w) {
            int j = w * 64 + lane;
            bool pred = false;
            if (j < nv && j > i) {
                float xx1 = fmaxf(r_x1, bx1[j]);
                float yy1 = fmaxf(r_y1, by1[j]);
                float xx2 = fminf(r_x2, bx2[j]);
                float yy2 = fminf(r_y2, by2[j]);
                float iw = fmaxf(xx2 - xx1, 0.0f);
                float ih = fmaxf(yy2 - yy1, 0.0f);
                float inter = iw * ih;
                float uni = (r_ar + bar[j]) - inter;
                pred = (uni > 0.0f) && (inter / uni > 0.45f);
            }
            unsigned long long m = __ballot(pred);
            if (lane == 0) masks[i][w] = m;
        }
    }
    __syncthreads();

    // serial greedy suppression (bit ops only)
    if (tid == 0) {
        unsigned long long s0 = 0, s1 = 0, s2 = 0, s3 = 0;
        unsigned long long k0 = 0, k1 = 0, k2 = 0, k3 = 0;
        for (int i = 0; i < nv; ++i) {
            int w = i >> 6, bit = i & 63;
            unsigned long long sw = (w == 0) ? s0 : (w == 1) ? s1 : (w == 2) ? s2 : s3;
            if (vflag[i] && !((sw >> bit) & 1ull)) {
                if (w == 0) k0 |= 1ull << bit;
                else if (w == 1) k1 |= 1ull << bit;
                else if (w == 2) k2 |= 1ull << bit;
                else k3 |= 1ull << bit;
                s0 |= masks[i][0]; s1 |= masks[i][1]; s2 |= masks[i][2]; s3 |= masks[i][3];
            }
        }
        keepw[0] = k0; keepw[1] = k1; keepw[2] = k2; keepw[3] = k3;
        kpre[0] = 0;
        kpre[1] = (unsigned)__popcll(k0);
        kpre[2] = kpre[1] + (unsigned)__popcll(k1);
        kpre[3] = kpre[2] + (unsigned)__popcll(k2);
    }
    __syncthreads();

    if (tid < nv) {
        int w = tid >> 6, bit = tid & 63;
        if ((keepw[w] >> bit) & 1ull) {
            unsigned slot = kpre[w] + (unsigned)__popcll(keepw[w] & ((1ull << bit) - 1ull));
            outrow[slot * 5 + 0] = sc[tid];
            outrow[slot * 5 + 1] = bx1[tid];
            outrow[slot * 5 + 2] = by1[tid];
            outrow[slot * 5 + 3] = bx2[tid];
            outrow[slot * 5 + 4] = by2[tid];
        }
    }
    __syncthreads();

    for (int i = tid; i < K_ * 5 / 4; i += 256)
        ((float4*)obase)[i] = ((const float4*)outrow)[i];
}

// ---------------------------------------------------------------------------
extern "C" void kernel_launch(void* const* d_in, const int* in_sizes, int n_in,
                              void* d_out, int out_size, void* d_ws, size_t ws_size,
                              hipStream_t stream) {
    const float* loc   = (const float*)d_in[0];
    const float* conf  = (const float*)d_in[1];
    const float* prior = (const float*)d_in[2];
    float* out = (float*)d_out;

    char* ws = (char*)d_ws;
    const size_t candBytes = (size_t)B_ * C_ * CAP * sizeof(unsigned long long); // 10.6 MB
    unsigned long long* cand = (unsigned long long*)ws;
    unsigned* cnt   = (unsigned*)(ws + candBytes);            // B_*C_ counters
    unsigned* bflag = cnt + (size_t)B_ * C_;                  // B_ flags (contiguous)

    hipMemsetAsync(cnt, 0, (size_t)(B_ * C_ + B_) * sizeof(unsigned), stream);

    k_filter<<<B_ * NCH, 256, 0, stream>>>(conf, cand, cnt, bflag);
    k_nms   <<<B_ * C_,  256, 0, stream>>>(cand, cnt, bflag, conf, loc, prior, out);
}

// Round 4
// 214.371 us; speedup vs baseline: 3.0024x; 1.0684x over previous
//
#include <hip/hip_runtime.h>
#include <hip/hip_bf16.h>
#include <math.h>

// Problem constants (fixed by setup_inputs)
constexpr int B_ = 32;
constexpr int P_ = 24564;
constexpr int C_ = 81;
constexpr int K_ = 200;

constexpr int NCH = 64;           // chunks per image
constexpr int CPR = 384;          // rows per chunk; 64*384 = 24576 >= 24564
constexpr int SCAP = 1024;        // per-block LDS staging capacity (expect ~404)
constexpr int CAP  = 512;         // per-task candidate capacity (expect ~322)
constexpr int NSORT = 512;        // bitonic sort width (CAP)
constexpr float T_SEL = 0.9869f;  // static prune threshold; mean count ~322 > 200 (6.8 sigma)
                                  // soundness: count>=200 above T => true top-200 all > T;
                                  // violations detected at runtime -> exact fallback.

__device__ inline unsigned long long shfl64(unsigned long long v, int src) {
    int lo = __shfl((int)(unsigned)(v & 0xffffffffull), src, 64);
    int hi = __shfl((int)(unsigned)(v >> 32), src, 64);
    return ((unsigned long long)(unsigned)hi << 32) | (unsigned)lo;
}

// ---------------------------------------------------------------------------
// K1 (only conf pass): stream slab coalesced, stage score>T candidates in LDS,
// reserve per-class ranges with ONE global atomic per (block,class), scatter.
// ---------------------------------------------------------------------------
__global__ __launch_bounds__(256) void k_filter(const float* __restrict__ conf,
                                                unsigned long long* __restrict__ cand,
                                                unsigned* __restrict__ cnt,
                                                unsigned* __restrict__ bflag) {
    __shared__ unsigned long long skey[SCAP];   // 8 KB
    __shared__ unsigned short scls[SCAP];       // 2 KB
    __shared__ unsigned scnt[C_], sbase[C_], scnt2[C_];
    __shared__ unsigned sn;
    const int bid = blockIdx.x;
    const int b = bid / NCH, ch = bid % NCH;
    const int tid = threadIdx.x;

    for (int i = tid; i < C_; i += 256) { scnt[i] = 0; scnt2[i] = 0; }
    if (tid == 0) sn = 0;
    __syncthreads();

    const int p0 = ch * CPR;
    const int rows = min(CPR, P_ - p0);
    const float* slab = conf + ((size_t)b * P_ + (size_t)p0) * C_;
    const int n4 = rows * C_ / 4;               // rows%4==0 -> exact
    for (int g = tid; g < n4; g += 256) {
        float4 v = ((const float4*)slab)[g];
        int e = g * 4;
        int c = e % C_;
        int pl = e / C_;
        float s[4] = {v.x, v.y, v.z, v.w};
#pragma unroll
        for (int j = 0; j < 4; ++j) {
            int cj = c + j, pj = pl;
            if (cj >= C_) { cj -= C_; pj += 1; }
            float sv = s[j];
            if (sv > T_SEL && cj != 0) {        // class 0 (background) never output
                unsigned pos = atomicAdd(&sn, 1u);
                if (pos < (unsigned)SCAP) {
                    unsigned pg = (unsigned)(p0 + pj);
                    skey[pos] = ((unsigned long long)__float_as_uint(sv) << 32) | (~pg);
                    scls[pos] = (unsigned short)cj;
                    atomicAdd(&scnt[cj], 1u);
                } else {
                    bflag[b] = 1u;              // staging overflow -> image fallback
                }
            }
        }
    }
    __syncthreads();
    if (tid < C_) sbase[tid] = scnt[tid] ? atomicAdd(&cnt[b * C_ + tid], scnt[tid]) : 0u;
    __syncthreads();
    const int m = (int)min(sn, (unsigned)SCAP);
    for (int i = tid; i < m; i += 256) {
        int c = scls[i];
        unsigned pos = sbase[c] + atomicAdd(&scnt2[c], 1u);
        if (pos < (unsigned)CAP)
            cand[((size_t)(b * C_ + c)) * CAP + pos] = skey[i];
        // pos >= CAP  =>  cnt[task] > CAP  => task falls back (detected in k_nms)
    }
}

// ---------------------------------------------------------------------------
// K2: per-task bitonic sort (barrier-light), decode, IoU masks with
// register-cached column boxes, scalar-register greedy scan, coalesced write.
// ---------------------------------------------------------------------------
__global__ __launch_bounds__(256) void k_nms(const unsigned long long* __restrict__ cand,
                                             const unsigned* __restrict__ cnt,
                                             const unsigned* __restrict__ bflag,
                                             const float* __restrict__ conf,
                                             const float* __restrict__ loc,
                                             const float* __restrict__ prior,
                                             float* __restrict__ out) {
#pragma clang fp contract(off)
    __shared__ unsigned long long buf[NSORT];           // 4 KB (sorted in place)
    __shared__ float sc[K_], bx1[K_], by1[K_], bx2[K_], by2[K_], bar[K_];
    __shared__ unsigned long long masks[K_][4];         // 6.4 KB
    __shared__ unsigned long long sh_prefix;
    __shared__ unsigned sh_rank, sh_cnt2;
    __shared__ unsigned long long keepw[4];
    __shared__ unsigned kpre[4];
    __shared__ unsigned char vflag[K_];
    __shared__ __align__(16) float outrow[K_ * 5];      // 4 KB

    // fallback-only radix scratch aliased onto masks (masks unused until IoU)
    unsigned* rs_hist = (unsigned*)&masks[0][0];
    unsigned* rs_sf   = rs_hist + 256;

    const int bid = blockIdx.x;
    const int b = bid / C_, c = bid % C_;
    const int tid = threadIdx.x;
    float* obase = out + ((size_t)(b * C_ + c)) * (K_ * 5);

    if (c == 0) {                               // background rows: all zeros
        float4 z = make_float4(0.f, 0.f, 0.f, 0.f);
        for (int i = tid; i < K_ * 5 / 4; i += 256) ((float4*)obase)[i] = z;
        return;
    }
    for (int i = tid; i < K_ * 5; i += 256) outrow[i] = 0.0f;

    const int task = b * C_ + c;
    const unsigned cn = cnt[task];
    const bool fb = (bflag[b] != 0u) || (cn < (unsigned)K_) || (cn > (unsigned)CAP);

    int n;
    if (!fb) {
        n = (int)cn;                            // 200 <= n <= CAP
        for (int i = tid; i < NSORT; i += 256)
            buf[i] = (i < n) ? cand[(size_t)task * CAP + i] : 0ull;
        __syncthreads();
    } else {
        // ---- exact fallback from the strided global column (rare/never) ----
        for (int i = tid; i < NSORT; i += 256) buf[i] = 0ull;
        const float* col = conf + (size_t)b * P_ * C_ + c;
        unsigned lc = 0;
        for (int p = tid; p < P_; p += 256)
            if (col[(size_t)p * C_] > 0.01f) lc++;
        rs_sf[tid] = lc;
        __syncthreads();
        for (int off = 128; off > 0; off >>= 1) {
            if (tid < off) rs_sf[tid] += rs_sf[tid + off];
            __syncthreads();
        }
        const unsigned total = rs_sf[0];
        unsigned long long t200v = 1ull;
        if (total > (unsigned)K_) {
            if (tid == 0) { sh_prefix = 0ull; sh_rank = (unsigned)K_; }
            __syncthreads();
            for (int d = 7; d >= 0; --d) {
                rs_hist[tid] = 0;
                __syncthreads();
                const unsigned long long pref = sh_prefix;
                const unsigned rank = sh_rank;
                for (int p = tid; p < P_; p += 256) {
                    float sv = col[(size_t)p * C_];
                    if (sv > 0.01f) {
                        unsigned long long key =
                            ((unsigned long long)__float_as_uint(sv) << 32) | (~(unsigned)p);
                        bool match = (d == 7) || (((key ^ pref) >> ((d + 1) * 8)) == 0ull);
                        if (match) atomicAdd(&rs_hist[(unsigned)((key >> (d * 8)) & 255ull)], 1u);
                    }
                }
                __syncthreads();
                rs_sf[tid] = rs_hist[tid];
                __syncthreads();
                for (int off = 1; off < 256; off <<= 1) {
                    unsigned v2 = (tid + off < 256) ? rs_sf[tid + off] : 0u;
                    __syncthreads();
                    rs_sf[tid] += v2;
                    __syncthreads();
                }
                if (rs_sf[tid] >= rank && (tid == 255 || rs_sf[tid + 1] < rank)) {
                    sh_prefix = pref | ((unsigned long long)tid << (d * 8));
                    sh_rank = rank - ((tid == 255) ? 0u : rs_sf[tid + 1]);
                }
                __syncthreads();
            }
            t200v = sh_prefix;
        }
        if (tid == 0) sh_cnt2 = 0;
        __syncthreads();
        for (int p = tid; p < P_; p += 256) {
            float sv = col[(size_t)p * C_];
            if (sv > 0.01f) {
                unsigned long long key =
                    ((unsigned long long)__float_as_uint(sv) << 32) | (~(unsigned)p);
                if (key >= t200v) {
                    unsigned pos = atomicAdd(&sh_cnt2, 1u);
                    if (pos < (unsigned)CAP) buf[pos] = key;   // exactly <=200 qualify
                }
            }
        }
        __syncthreads();
        n = (int)min(sh_cnt2, (unsigned)CAP);
    }

    // ---- bitonic sort ascending over NSORT=512, barrier only on cross-wave
    // stages (j>=128). For j<=64 each wave's compare-exchange pairs stay inside
    // its own 128-element span; per-wave DS ops execute in order, compiler
    // reordering pinned by the asm memory barrier.
    {
        bool after_cross = false;
        for (int k = 2; k <= NSORT; k <<= 1) {
            for (int j = k >> 1; j > 0; j >>= 1) {
                bool cross = (j >= 128);
                if (cross || after_cross) __syncthreads();
                else asm volatile("" ::: "memory");
                int e = ((tid & ~(j - 1)) << 1) | (tid & (j - 1));
                int pp = e | j;
                bool up = ((e & k) == 0);
                unsigned long long a = buf[e], bb = buf[pp];
                unsigned long long lo = a < bb ? a : bb;
                unsigned long long hi = a < bb ? bb : a;
                buf[e]  = up ? lo : hi;
                buf[pp] = up ? hi : lo;
                asm volatile("" ::: "memory");
                after_cross = cross;
            }
        }
        __syncthreads();
    }

    const int nsel = min(n, K_);

    // decode rank-r candidates (descending = buf[NSORT-1-r])
    if (tid < K_) {
        const int r = tid;
        bool v = (r < nsel);
        float score = 0.f, x1 = 0.f, y1 = 0.f, x2 = 0.f, y2 = 0.f, ar = 0.f;
        if (v) {
            unsigned long long key = buf[NSORT - 1 - r];
            unsigned ub = (unsigned)(key >> 32);
            unsigned p = ~((unsigned)key);
            score = __uint_as_float(ub);
            v = ((ub & 0x7F800000u) != 0x7F800000u);   // isfinite
            const float4 l4 = ((const float4*)loc)[(size_t)b * P_ + p];
            const float4 p4 = ((const float4*)prior)[p];
            float cx = p4.x + (l4.x * 0.1f) * p4.z;
            float cy = p4.y + (l4.y * 0.1f) * p4.w;
            float w  = p4.z * expf(l4.z * 0.2f);
            float h  = p4.w * expf(l4.w * 0.2f);
            x1 = cx - w * 0.5f;
            y1 = cy - h * 0.5f;
            x2 = x1 + w;
            y2 = y1 + h;
            ar = (x2 - x1) * (y2 - y1);
        }
        sc[r] = score; bx1[r] = x1; by1[r] = y1; bx2[r] = x2; by2[r] = y2; bar[r] = ar;
        vflag[r] = v ? (unsigned char)1 : (unsigned char)0;
    }
    __syncthreads();

    // ---- IoU suppression bitmasks, column boxes register-cached ----------
    const int nv = nsel;
    const int wid = tid >> 6, lane = tid & 63;

    float jx1[4], jy1[4], jx2[4], jy2[4], jar[4];
#pragma unroll
    for (int w = 0; w < 4; ++w) {
        int j = w * 64 + lane;
        bool in = (j < K_);
        jx1[w] = in ? bx1[j] : 0.f;
        jy1[w] = in ? by1[j] : 0.f;
        jx2[w] = in ? bx2[j] : 0.f;
        jy2[w] = in ? by2[j] : 0.f;
        jar[w] = in ? bar[j] : 0.f;
    }

    for (int idx = tid; idx < K_ * 4; idx += 256) {
        int i = idx >> 2, w = idx & 3;
        if (w < (i >> 6)) masks[i][w] = 0ull;
    }
    for (int i = wid; i < nv; i += 4) {
        float r_x1 = bx1[i], r_y1 = by1[i], r_x2 = bx2[i], r_y2 = by2[i], r_ar = bar[i];
        const int w0 = i >> 6;
#pragma unroll
        for (int w = 0; w < 4; ++w) {
            if (w >= w0) {
                int j = w * 64 + lane;
                bool pred = false;
                if (j < nv && j > i) {
                    float xx1 = fmaxf(r_x1, jx1[w]);
                    float yy1 = fmaxf(r_y1, jy1[w]);
                    float xx2 = fminf(r_x2, jx2[w]);
                    float yy2 = fminf(r_y2, jy2[w]);
                    float iw = fmaxf(xx2 - xx1, 0.0f);
                    float ih = fmaxf(yy2 - yy1, 0.0f);
                    float inter = iw * ih;
                    float uni = (r_ar + jar[w]) - inter;
                    pred = (uni > 0.0f) && (inter / uni > 0.45f);
                }
                unsigned long long m = __ballot(pred);
                if (lane == 0) masks[i][w] = m;
            }
        }
    }
    __syncthreads();

    // ---- greedy suppression: wave 0, masks register-cached, kept-only loop.
    if (tid < 64) {
        const int l = tid;
        unsigned long long ma0, ma1, ma2, ma3;   // row l
        unsigned long long mb0, mb1, mb2, mb3;   // row 64+l
        unsigned long long mc0, mc1, mc2, mc3;   // row 128+l
        unsigned long long md0, md1, md2, md3;   // row 192+l
        ma0 = masks[l][0];       ma1 = masks[l][1];       ma2 = masks[l][2];       ma3 = masks[l][3];
        mb0 = masks[64 + l][0];  mb1 = masks[64 + l][1];  mb2 = masks[64 + l][2];  mb3 = masks[64 + l][3];
        { int r = 128 + l; bool in = r < K_;
          mc0 = in ? masks[r][0] : 0ull; mc1 = in ? masks[r][1] : 0ull;
          mc2 = in ? masks[r][2] : 0ull; mc3 = in ? masks[r][3] : 0ull; }
        { int r = 192 + l; bool in = r < K_;
          md0 = in ? masks[r][0] : 0ull; md1 = in ? masks[r][1] : 0ull;
          md2 = in ? masks[r][2] : 0ull; md3 = in ? masks[r][3] : 0ull; }

        unsigned long long S0, S1, S2, S3, K0 = 0, K1 = 0, K2 = 0, K3 = 0;
        S0 = ~__ballot((l       < nv) && vflag[l]);
        S1 = ~__ballot((64 + l  < nv) && vflag[64 + l]);
        S2 = ~__ballot((128 + l < nv) && (128 + l < K_) && vflag[(128 + l) < K_ ? 128 + l : 0]);
        S3 = ~__ballot((192 + l < nv) && (192 + l < K_) && vflag[(192 + l) < K_ ? 192 + l : 0]);

        while (true) {
            int i = -1;
            unsigned long long t;
            if ((t = ~S0) != 0ull)      i = (int)__builtin_ctzll(t);
            else if ((t = ~S1) != 0ull) i = 64 + (int)__builtin_ctzll(t);
            else if ((t = ~S2) != 0ull) i = 128 + (int)__builtin_ctzll(t);
            else if ((t = ~S3) != 0ull) i = 192 + (int)__builtin_ctzll(t);
            if (i < 0) break;
            const int slot = i >> 6, src = i & 63;
            const unsigned long long bit = 1ull << src;
            unsigned long long r0, r1, r2, r3;
            if (slot == 0)      { K0 |= bit; S0 |= bit;
                r0 = shfl64(ma0, src); r1 = shfl64(ma1, src); r2 = shfl64(ma2, src); r3 = shfl64(ma3, src); }
            else if (slot == 1) { K1 |= bit; S1 |= bit;
                r0 = shfl64(mb0, src); r1 = shfl64(mb1, src); r2 = shfl64(mb2, src); r3 = shfl64(mb3, src); }
            else if (slot == 2) { K2 |= bit; S2 |= bit;
                r0 = shfl64(mc0, src); r1 = shfl64(mc1, src); r2 = shfl64(mc2, src); r3 = shfl64(mc3, src); }
            else                { K3 |= bit; S3 |= bit;
                r0 = shfl64(md0, src); r1 = shfl64(md1, src); r2 = shfl64(md2, src); r3 = shfl64(md3, src); }
            S0 |= r0; S1 |= r1; S2 |= r2; S3 |= r3;
        }
        if (l == 0) {
            keepw[0] = K0; keepw[1] = K1; keepw[2] = K2; keepw[3] = K3;
            kpre[0] = 0;
            kpre[1] = (unsigned)__popcll(K0);
            kpre[2] = kpre[1] + (unsigned)__popcll(K1);
            kpre[3] = kpre[2] + (unsigned)__popcll(K2);
        }
    }
    __syncthreads();

    if (tid < nv) {
        int w = tid >> 6, bit = tid & 63;
        if ((keepw[w] >> bit) & 1ull) {
            unsigned slot = kpre[w] + (unsigned)__popcll(keepw[w] & ((1ull << bit) - 1ull));
            outrow[slot * 5 + 0] = sc[tid];
            outrow[slot * 5 + 1] = bx1[tid];
            outrow[slot * 5 + 2] = by1[tid];
            outrow[slot * 5 + 3] = bx2[tid];
            outrow[slot * 5 + 4] = by2[tid];
        }
    }
    __syncthreads();

    for (int i = tid; i < K_ * 5 / 4; i += 256)
        ((float4*)obase)[i] = ((const float4*)outrow)[i];
}

// ---------------------------------------------------------------------------
extern "C" void kernel_launch(void* const* d_in, const int* in_sizes, int n_in,
                              void* d_out, int out_size, void* d_ws, size_t ws_size,
                              hipStream_t stream) {
    const float* loc   = (const float*)d_in[0];
    const float* conf  = (const float*)d_in[1];
    const float* prior = (const float*)d_in[2];
    float* out = (float*)d_out;

    char* ws = (char*)d_ws;
    const size_t candBytes = (size_t)B_ * C_ * CAP * sizeof(unsigned long long); // 10.6 MB
    unsigned long long* cand = (unsigned long long*)ws;
    unsigned* cnt   = (unsigned*)(ws + candBytes);            // B_*C_ counters
    unsigned* bflag = cnt + (size_t)B_ * C_;                  // B_ flags (contiguous)

    hipMemsetAsync(cnt, 0, (size_t)(B_ * C_ + B_) * sizeof(unsigned), stream);

    k_filter<<<B_ * NCH, 256, 0, stream>>>(conf, cand, cnt, bflag);
    k_nms   <<<B_ * C_,  256, 0, stream>>>(cand, cnt, bflag, conf, loc, prior, out);
}

// Round 5
// 159.553 us; speedup vs baseline: 4.0340x; 1.3436x over previous
//
#include <hip/hip_runtime.h>
#include <hip/hip_bf16.h>
#include <math.h>

// Problem constants (fixed by setup_inputs)
constexpr int B_ = 32;
constexpr int P_ = 24564;
constexpr int C_ = 81;
constexpr int K_ = 200;

constexpr int NCH = 64;           // chunks per image
constexpr int CPR = 384;          // rows per chunk; 64*384 = 24576 >= 24564
constexpr int SCAP = 1024;        // per-block LDS staging capacity (expect ~404)
constexpr int CAP  = 512;         // per-task candidate capacity (expect ~322)
constexpr int NSORT = 512;        // fallback sort width
constexpr float T_SEL = 0.9869f;  // static prune threshold; mean count ~322 > 200 (6.8 sigma)
                                  // soundness: count>=200 above T => true top-200 all > T;
                                  // violations detected at runtime -> exact fallback.
// All candidate scores lie in (T_SEL, 1.0) => float bits[31:19] == 0x7EF for every
// candidate => key bits[63:51] constant => bits[50:43] are the next radix digit.

// ---------------------------------------------------------------------------
// K1 (only conf pass): stream slab coalesced, stage score>T candidates in LDS,
// reserve per-class ranges with ONE global atomic per (block,class), scatter.
// ---------------------------------------------------------------------------
__global__ __launch_bounds__(256) void k_filter(const float* __restrict__ conf,
                                                unsigned long long* __restrict__ cand,
                                                unsigned* __restrict__ cnt,
                                                unsigned* __restrict__ bflag) {
    __shared__ unsigned long long skey[SCAP];   // 8 KB
    __shared__ unsigned short scls[SCAP];       // 2 KB
    __shared__ unsigned scnt[C_], sbase[C_], scnt2[C_];
    __shared__ unsigned sn;
    const int bid = blockIdx.x;
    const int b = bid / NCH, ch = bid % NCH;
    const int tid = threadIdx.x;

    for (int i = tid; i < C_; i += 256) { scnt[i] = 0; scnt2[i] = 0; }
    if (tid == 0) sn = 0;
    __syncthreads();

    const int p0 = ch * CPR;
    const int rows = min(CPR, P_ - p0);
    const float* slab = conf + ((size_t)b * P_ + (size_t)p0) * C_;
    const int n4 = rows * C_ / 4;               // rows%4==0 -> exact
    for (int g = tid; g < n4; g += 256) {
        float4 v = ((const float4*)slab)[g];
        int e = g * 4;
        int c = e % C_;
        int pl = e / C_;
        float s[4] = {v.x, v.y, v.z, v.w};
#pragma unroll
        for (int j = 0; j < 4; ++j) {
            int cj = c + j, pj = pl;
            if (cj >= C_) { cj -= C_; pj += 1; }
            float sv = s[j];
            if (sv > T_SEL && cj != 0) {        // class 0 (background) never output
                unsigned pos = atomicAdd(&sn, 1u);
                if (pos < (unsigned)SCAP) {
                    unsigned pg = (unsigned)(p0 + pj);
                    skey[pos] = ((unsigned long long)__float_as_uint(sv) << 32) | (~pg);
                    scls[pos] = (unsigned short)cj;
                    atomicAdd(&scnt[cj], 1u);
                } else {
                    bflag[b] = 1u;              // staging overflow -> image fallback
                }
            }
        }
    }
    __syncthreads();
    if (tid < C_) sbase[tid] = scnt[tid] ? atomicAdd(&cnt[b * C_ + tid], scnt[tid]) : 0u;
    __syncthreads();
    const int m = (int)min(sn, (unsigned)SCAP);
    for (int i = tid; i < m; i += 256) {
        int c = scls[i];
        unsigned pos = sbase[c] + atomicAdd(&scnt2[c], 1u);
        if (pos < (unsigned)CAP)
            cand[((size_t)(b * C_ + c)) * CAP + pos] = skey[i];
        // pos >= CAP  =>  cnt[task] > CAP  => task falls back (detected in k_nms)
    }
}

// ---------------------------------------------------------------------------
// K2: per-task radix-digit cut -> 256-wide bitonic (exact top-200), decode,
// IoU masks (register-cached columns), uniform wave-0 greedy scan, write.
// ---------------------------------------------------------------------------
__global__ __launch_bounds__(256) void k_nms(const unsigned long long* __restrict__ cand,
                                             const unsigned* __restrict__ cnt,
                                             const unsigned* __restrict__ bflag,
                                             const float* __restrict__ conf,
                                             const float* __restrict__ loc,
                                             const float* __restrict__ prior,
                                             float* __restrict__ out) {
#pragma clang fp contract(off)
    __shared__ __align__(16) unsigned long long masks[K_][4];   // 6400 B
    __shared__ __align__(16) float outrow[1024];                // 4096 B (padded; aliases fb buf)
    __shared__ unsigned long long top[256];                     // 2048 B
    __shared__ float sc[K_], bx1[K_], by1[K_], bx2[K_], by2[K_], bar[K_];
    __shared__ unsigned char vflag[K_];
    __shared__ unsigned long long keepw[4];
    __shared__ unsigned kpre[4];
    __shared__ unsigned long long sh_prefix;
    __shared__ unsigned sh_rank, sh_cnt2, sh_cut, sh_fat;

    unsigned long long* buf = (unsigned long long*)outrow;      // fb-only staging (512 u64)
    unsigned* rs_hist = (unsigned*)&masks[0][0];                // cut/fb scratch (pre-IoU only)
    unsigned* rs_sf   = rs_hist + 256;

    const int bid = blockIdx.x;
    const int b = bid / C_, c = bid % C_;
    const int tid = threadIdx.x;
    float* obase = out + ((size_t)(b * C_ + c)) * (K_ * 5);

    if (c == 0) {                               // background rows: all zeros
        float4 z = make_float4(0.f, 0.f, 0.f, 0.f);
        for (int i = tid; i < K_ * 5 / 4; i += 256) ((float4*)obase)[i] = z;
        return;
    }

    const int task = b * C_ + c;
    const unsigned long long* crow = cand + (size_t)task * CAP;
    const unsigned cn = cnt[task];
    const bool fb = (bflag[b] != 0u) || (cn < (unsigned)K_) || (cn > (unsigned)CAP);

    int n;
    if (!fb) {
        n = (int)cn;                            // 200 <= n <= CAP
    } else {
        // ---- exact fallback from the strided global column (rare/never) ----
        for (int i = tid; i < NSORT; i += 256) buf[i] = 0ull;
        const float* col = conf + (size_t)b * P_ * C_ + c;
        unsigned lc = 0;
        for (int p = tid; p < P_; p += 256)
            if (col[(size_t)p * C_] > 0.01f) lc++;
        rs_sf[tid] = lc;
        __syncthreads();
        for (int off = 128; off > 0; off >>= 1) {
            if (tid < off) rs_sf[tid] += rs_sf[tid + off];
            __syncthreads();
        }
        const unsigned total = rs_sf[0];
        unsigned long long t200v = 1ull;
        if (total > (unsigned)K_) {
            if (tid == 0) { sh_prefix = 0ull; sh_rank = (unsigned)K_; }
            __syncthreads();
            for (int d = 7; d >= 0; --d) {
                rs_hist[tid] = 0;
                __syncthreads();
                const unsigned long long pref = sh_prefix;
                const unsigned rank = sh_rank;
                for (int p = tid; p < P_; p += 256) {
                    float sv = col[(size_t)p * C_];
                    if (sv > 0.01f) {
                        unsigned long long key =
                            ((unsigned long long)__float_as_uint(sv) << 32) | (~(unsigned)p);
                        bool match = (d == 7) || (((key ^ pref) >> ((d + 1) * 8)) == 0ull);
                        if (match) atomicAdd(&rs_hist[(unsigned)((key >> (d * 8)) & 255ull)], 1u);
                    }
                }
                __syncthreads();
                rs_sf[tid] = rs_hist[tid];
                __syncthreads();
                for (int off = 1; off < 256; off <<= 1) {
                    unsigned v2 = (tid + off < 256) ? rs_sf[tid + off] : 0u;
                    __syncthreads();
                    rs_sf[tid] += v2;
                    __syncthreads();
                }
                if (rs_sf[tid] >= rank && (tid == 255 || rs_sf[tid + 1] < rank)) {
                    sh_prefix = pref | ((unsigned long long)tid << (d * 8));
                    sh_rank = rank - ((tid == 255) ? 0u : rs_sf[tid + 1]);
                }
                __syncthreads();
            }
            t200v = sh_prefix;
        }
        if (tid == 0) sh_cnt2 = 0;
        __syncthreads();
        for (int p = tid; p < P_; p += 256) {
            float sv = col[(size_t)p * C_];
            if (sv > 0.01f) {
                unsigned long long key =
                    ((unsigned long long)__float_as_uint(sv) << 32) | (~(unsigned)p);
                if (key >= t200v) {
                    unsigned pos = atomicAdd(&sh_cnt2, 1u);
                    if (pos < (unsigned)CAP) buf[pos] = key;   // <=200 qualify (keys unique)
                }
            }
        }
        __syncthreads();
        n = (int)min(sh_cnt2, (unsigned)CAP);   // <= 200
    }

    // ---- select working set (<=256) via exact radix-digit cut -------------
    bool fat = false;
    if (n <= 256) {
        top[tid] = (tid < n) ? (fb ? buf[tid] : crow[tid]) : 0ull;
        __syncthreads();
    } else {
        if (tid == 0) { sh_fat = 0u; sh_cnt2 = 0u; }
        rs_hist[tid] = 0u;
        __syncthreads();
        for (int i = tid; i < n; i += 256)
            atomicAdd(&rs_hist[(unsigned)((crow[i] >> 43) & 255ull)], 1u);
        __syncthreads();
        rs_sf[tid] = rs_hist[tid];
        __syncthreads();
        for (int off = 1; off < 256; off <<= 1) {
            unsigned v2 = (tid + off < 256) ? rs_sf[tid + off] : 0u;
            __syncthreads();
            rs_sf[tid] += v2;
            __syncthreads();
        }
        // largest digit t with suffix >= 200 (exists since suffix(0)=n>=257)
        if (rs_sf[tid] >= (unsigned)K_ && (tid == 255 || rs_sf[tid + 1] < (unsigned)K_)) {
            sh_cut = (unsigned)tid;
            sh_fat = (rs_sf[tid] > 256u) ? 1u : 0u;
        }
        __syncthreads();
        fat = (sh_fat != 0u);
        if (!fat) {
            const unsigned cut = sh_cut;
            top[tid] = 0ull;
            __syncthreads();
            for (int i = tid; i < n; i += 256) {
                unsigned long long key = crow[i];
                if ((unsigned)((key >> 43) & 255ull) >= cut)
                    top[atomicAdd(&sh_cnt2, 1u)] = key;   // 200..256 selected, exact set
            }
            __syncthreads();
        } else {
            // degenerate digit distribution: exact 512-wide sort (rare path)
            for (int i = tid; i < NSORT; i += 256)
                buf[i] = (i < n) ? crow[i] : 0ull;
            __syncthreads();
        }
    }

    // ---- sort ---------------------------------------------------------------
    if (!fat) {
        // 256-wide bitonic, threads 0-127 active; barrier only around cross-wave
        // stages (j>=128); in-wave DS ordering covers the rest.
        bool after_cross = false;
        for (int k = 2; k <= 256; k <<= 1) {
            for (int j = k >> 1; j > 0; j >>= 1) {
                bool cross = (j >= 128);
                if (cross || after_cross) __syncthreads();
                else asm volatile("" ::: "memory");
                if (tid < 128) {
                    int e = ((tid & ~(j - 1)) << 1) | (tid & (j - 1));
                    int pp = e | j;
                    bool up = ((e & k) == 0);
                    unsigned long long a = top[e], bb = top[pp];
                    unsigned long long lo = a < bb ? a : bb;
                    unsigned long long hi = a < bb ? bb : a;
                    top[e]  = up ? lo : hi;
                    top[pp] = up ? hi : lo;
                }
                asm volatile("" ::: "memory");
                after_cross = cross;
            }
        }
        __syncthreads();
    } else {
        for (int k = 2; k <= NSORT; k <<= 1) {
            for (int j = k >> 1; j > 0; j >>= 1) {
                __syncthreads();
                int e = ((tid & ~(j - 1)) << 1) | (tid & (j - 1));
                int pp = e | j;
                bool up = ((e & k) == 0);
                unsigned long long a = buf[e], bb = buf[pp];
                unsigned long long lo = a < bb ? a : bb;
                unsigned long long hi = a < bb ? bb : a;
                buf[e]  = up ? lo : hi;
                buf[pp] = up ? hi : lo;
            }
        }
        __syncthreads();
    }

    const int nsel = min(n, K_);
    const unsigned long long* srt = fat ? buf : top;
    const int srtN = fat ? NSORT : 256;

    // decode rank-r candidates (descending = srt[srtN-1-r])
    if (tid < K_) {
        const int r = tid;
        bool v = (r < nsel);
        float score = 0.f, x1 = 0.f, y1 = 0.f, x2 = 0.f, y2 = 0.f, ar = 0.f;
        if (v) {
            unsigned long long key = srt[srtN - 1 - r];
            unsigned ub = (unsigned)(key >> 32);
            unsigned p = ~((unsigned)key);
            score = __uint_as_float(ub);
            v = ((ub & 0x7F800000u) != 0x7F800000u);   // isfinite
            const float4 l4 = ((const float4*)loc)[(size_t)b * P_ + p];
            const float4 p4 = ((const float4*)prior)[p];
            float cx = p4.x + (l4.x * 0.1f) * p4.z;
            float cy = p4.y + (l4.y * 0.1f) * p4.w;
            float w  = p4.z * expf(l4.z * 0.2f);
            float h  = p4.w * expf(l4.w * 0.2f);
            x1 = cx - w * 0.5f;
            y1 = cy - h * 0.5f;
            x2 = x1 + w;
            y2 = y1 + h;
            ar = (x2 - x1) * (y2 - y1);
        }
        sc[r] = score; bx1[r] = x1; by1[r] = y1; bx2[r] = x2; by2[r] = y2; bar[r] = ar;
        vflag[r] = v ? (unsigned char)1 : (unsigned char)0;
    }
    __syncthreads();                            // decode done; buf dead -> outrow reusable

    for (int i = tid; i < 1024; i += 256) outrow[i] = 0.0f;

    // ---- IoU suppression bitmasks, column boxes register-cached ------------
    const int nv = nsel;
    const int wid = tid >> 6, lane = tid & 63;

    float jx1[4], jy1[4], jx2[4], jy2[4], jar[4];
#pragma unroll
    for (int w = 0; w < 4; ++w) {
        int j = w * 64 + lane;
        bool in = (j < K_);
        jx1[w] = in ? bx1[j] : 0.f;
        jy1[w] = in ? by1[j] : 0.f;
        jx2[w] = in ? bx2[j] : 0.f;
        jy2[w] = in ? by2[j] : 0.f;
        jar[w] = in ? bar[j] : 0.f;
    }

    for (int idx = tid; idx < K_ * 4; idx += 256) {
        int i = idx >> 2, w = idx & 3;
        if (w < (i >> 6)) masks[i][w] = 0ull;
    }
    for (int i = wid; i < nv; i += 4) {
        float r_x1 = bx1[i], r_y1 = by1[i], r_x2 = bx2[i], r_y2 = by2[i], r_ar = bar[i];
        const int w0 = i >> 6;
#pragma unroll
        for (int w = 0; w < 4; ++w) {
            if (w >= w0) {
                int j = w * 64 + lane;
                bool pred = false;
                if (j < nv && j > i) {
                    float xx1 = fmaxf(r_x1, jx1[w]);
                    float yy1 = fmaxf(r_y1, jy1[w]);
                    float xx2 = fminf(r_x2, jx2[w]);
                    float yy2 = fminf(r_y2, jy2[w]);
                    float iw = fmaxf(xx2 - xx1, 0.0f);
                    float ih = fmaxf(yy2 - yy1, 0.0f);
                    float inter = iw * ih;
                    float uni = (r_ar + jar[w]) - inter;
                    pred = (uni > 0.0f) && (inter / uni > 0.45f);
                }
                unsigned long long m = __ballot(pred);
                if (lane == 0) masks[i][w] = m;
            }
        }
    }
    __syncthreads();

    // ---- greedy suppression: wave 0, uniform lanes, kept-nonzero-rows loop.
    if (tid < 64) {
        const int l = tid;
        // valid ballots
        unsigned long long V0 = __ballot((l       < nv) && vflag[l]);
        unsigned long long V1 = __ballot((64 + l  < nv) && vflag[64 + l]);
        unsigned long long V2 = __ballot((128 + l < nv) && vflag[128 + l]);
        unsigned long long V3 = __ballot((192 + l < nv) && vflag[192 + l]);
        // nonzero-row ballots (rows >= nv unwritten -> guarded)
        auto rownz = [&](int r) -> bool {
            if (r >= nv) return false;
            return (masks[r][0] | masks[r][1] | masks[r][2] | masks[r][3]) != 0ull;
        };
        unsigned long long R0 = __ballot(rownz(l))       & V0;
        unsigned long long R1 = __ballot(rownz(64 + l))  & V1;
        unsigned long long R2 = __ballot(rownz(128 + l)) & V2;
        unsigned long long R3 = __ballot(rownz(192 + l)) & V3;

        unsigned long long S0 = 0, S1 = 0, S2 = 0, S3 = 0;
        while (true) {
            unsigned long long t;
            int i = -1;
            if ((t = R0 & ~S0) != 0ull)      i = (int)__builtin_ctzll(t);
            else if ((t = R1 & ~S1) != 0ull) i = 64 + (int)__builtin_ctzll(t);
            else if ((t = R2 & ~S2) != 0ull) i = 128 + (int)__builtin_ctzll(t);
            else if ((t = R3 & ~S3) != 0ull) i = 192 + (int)__builtin_ctzll(t);
            if (i < 0) break;
            const unsigned long long bit = 1ull << (i & 63);
            const int slot = i >> 6;
            if (slot == 0) R0 ^= bit; else if (slot == 1) R1 ^= bit;
            else if (slot == 2) R2 ^= bit; else R3 ^= bit;
            ulonglong2 m01 = *(const ulonglong2*)&masks[i][0];
            ulonglong2 m23 = *(const ulonglong2*)&masks[i][2];
            S0 |= m01.x; S1 |= m01.y; S2 |= m23.x; S3 |= m23.y;
        }
        if (l == 0) {
            unsigned long long K0 = V0 & ~S0, K1 = V1 & ~S1, K2 = V2 & ~S2, K3 = V3 & ~S3;
            keepw[0] = K0; keepw[1] = K1; keepw[2] = K2; keepw[3] = K3;
            kpre[0] = 0;
            kpre[1] = (unsigned)__popcll(K0);
            kpre[2] = kpre[1] + (unsigned)__popcll(K1);
            kpre[3] = kpre[2] + (unsigned)__popcll(K2);
        }
    }
    __syncthreads();

    if (tid < nv) {
        int w = tid >> 6, bit = tid & 63;
        if ((keepw[w] >> bit) & 1ull) {
            unsigned slot = kpre[w] + (unsigned)__popcll(keepw[w] & ((1ull << bit) - 1ull));
            outrow[slot * 5 + 0] = sc[tid];
            outrow[slot * 5 + 1] = bx1[tid];
            outrow[slot * 5 + 2] = by1[tid];
            outrow[slot * 5 + 3] = bx2[tid];
            outrow[slot * 5 + 4] = by2[tid];
        }
    }
    __syncthreads();

    for (int i = tid; i < K_ * 5 / 4; i += 256)
        ((float4*)obase)[i] = ((const float4*)outrow)[i];
}

// ---------------------------------------------------------------------------
extern "C" void kernel_launch(void* const* d_in, const int* in_sizes, int n_in,
                              void* d_out, int out_size, void* d_ws, size_t ws_size,
                              hipStream_t stream) {
    const float* loc   = (const float*)d_in[0];
    const float* conf  = (const float*)d_in[1];
    const float* prior = (const float*)d_in[2];
    float* out = (float*)d_out;

    char* ws = (char*)d_ws;
    const size_t candBytes = (size_t)B_ * C_ * CAP * sizeof(unsigned long long); // 10.6 MB
    unsigned long long* cand = (unsigned long long*)ws;
    unsigned* cnt   = (unsigned*)(ws + candBytes);            // B_*C_ counters
    unsigned* bflag = cnt + (size_t)B_ * C_;                  // B_ flags (contiguous)

    hipMemsetAsync(cnt, 0, (size_t)(B_ * C_ + B_) * sizeof(unsigned), stream);

    k_filter<<<B_ * NCH, 256, 0, stream>>>(conf, cand, cnt, bflag);
    k_nms   <<<B_ * C_,  256, 0, stream>>>(cand, cnt, bflag, conf, loc, prior, out);
}